// Round 17
// baseline (78.754 us; speedup 1.0000x reference)
//
#include <hip/hip_runtime.h>
#include <stdint.h>

typedef __attribute__((ext_vector_type(4))) int   i32x4;
typedef __attribute__((ext_vector_type(8))) int   i32x8;
typedef __attribute__((ext_vector_type(4))) float f32x4;

// BinaryConv: out = sign(conv2d(sign(x), sign(w), pad=1) + bias)
// R17: MX-FP4 implicit GEMM (verified bit-exact R14-R16, ~30us) + pack_xs4 v4:
// dword-wide LDS transpose with XOR-swizzled placement (f(c)=(c+(c>>3))&31):
// phase-1 = one ds_write_b32 per float4 (kills the 4-lane same-dword byte-write
// serialization of v2/v3), phase-2 dword reads hit all 32 banks (9 coprime 32).

#define NB 32
#define CC 256
#define HH 56
#define WW 56
#define OO 256
#define PH 58
#define PW 58
#define SS (HH*WW)      // 3136
#define KTOT 2304
#define BROW4 1152      // wsB4 row bytes: 9 taps x 128 ch-pairs
#define PIX4  128       // xs4 bytes per pixel

// ---- async global->LDS, 16B per lane; dest = wave-uniform base + lane*16 -----------
__device__ __forceinline__ void gload16(const void* g, void* l) {
    const __attribute__((address_space(1))) void* gp =
        reinterpret_cast<const __attribute__((address_space(1))) void*>(
            reinterpret_cast<uintptr_t>(g));
    __attribute__((address_space(3))) void* lp =
        reinterpret_cast<__attribute__((address_space(3))) void*>(
            static_cast<uintptr_t>(static_cast<uint32_t>(reinterpret_cast<uintptr_t>(l))));
    __builtin_amdgcn_global_load_lds(gp, lp, 16, 0, 0);
}

#define WAITVM(N) asm volatile("s_waitcnt vmcnt(" #N ")" ::: "memory")
#define WAITLGKM0() asm volatile("s_waitcnt lgkmcnt(0)" ::: "memory")

__device__ __forceinline__ uint32_t nib4u(float v) {
    return (v > 0.f) ? 0x2u : ((v < 0.f) ? 0xAu : 0x0u);   // e2m1 +1 / -1 / 0
}
__device__ __forceinline__ uint8_t nib4(float v) {
    return (uint8_t)nib4u(v);
}

// ============================ pack kernels ==========================================

// xs4: [n][ph][pw][c/2] fp4-pair bytes, border pixels = 0.
// Block = (h-pair, n), 512 threads. Phase 1: 448B-aligned 2-row channel segments,
// nibbles packed to u32 in regs, ONE ds_write_b32 at dword (q ^ f(c)), f(c)=(c+(c>>3))&31.
// Phase 2: per output u32, 8 dword reads at (d ^ f(c)) -- banks (d ^ (9*k4+j))&31 are
// all-distinct across the 32 lanes (9 coprime 32) -> conflict-free; coalesced u32 writes.
__global__ __launch_bounds__(512) void pack_xs4_kernel(const float* __restrict__ x,
                                                       uint8_t* __restrict__ xs4) {
    __shared__ uint32_t lt32[256 * 32];   // 32 KB
    const int t  = threadIdx.x;           // 0..511
    const int h0 = blockIdx.x * 2;        // 0,2,..,54
    const int n  = blockIdx.y;
    const float* xbase = x + (size_t)n * CC * SS + h0 * WW;

    // 256 ch x 28 float4 (2 rows) = 7168 quads, 14/thread, two 7-deep batches
#pragma unroll
    for (int half = 0; half < 2; ++half) {
        float4 v[7];
#pragma unroll
        for (int i = 0; i < 7; ++i) {
            int f = (half * 7 + i) * 512 + t;
            int c = f / 28, q = f - c * 28;
            v[i] = *(const float4*)(xbase + (size_t)c * SS + q * 4);
        }
#pragma unroll
        for (int i = 0; i < 7; ++i) {
            int f = (half * 7 + i) * 512 + t;
            int c = f / 28, q = f - c * 28;
            uint32_t r = nib4u(v[i].x) | (nib4u(v[i].y) << 8)
                       | (nib4u(v[i].z) << 16) | (nib4u(v[i].w) << 24);
            int fc = (c + (c >> 3)) & 31;
            lt32[c * 32 + (q ^ fc)] = r;
        }
    }
    __syncthreads();

    // interior pixels of rows h0, h0+1: 2 x 56 x 32 u32 = 3584
    for (int ot = t; ot < 2 * 56 * 32; ot += 512) {
        int k4  = ot & 31;                // u32 within pixel (8 channels)
        int idx = ot >> 5;                // 0..111 = row*56 + (pw-1)
        int row = idx / 56;
        int pwl = idx - row * 56;
        int d    = idx >> 2;              // dword within channel row
        int bsh  = (idx & 3) * 8;         // byte shift
        uint32_t r = 0;
#pragma unroll
        for (int j = 0; j < 4; ++j) {
            int c0 = 8 * k4 + 2 * j;
            int c1 = c0 + 1;
            uint32_t w0 = lt32[c0 * 32 + (d ^ ((c0 + (c0 >> 3)) & 31))];
            uint32_t w1 = lt32[c1 * 32 + (d ^ ((c1 + (c1 >> 3)) & 31))];
            uint32_t lo = (w0 >> bsh) & 0xFu;
            uint32_t hi = (w1 >> bsh) & 0xFu;
            r |= (lo | (hi << 4)) << (8 * j);
        }
        uint32_t* orow32 = (uint32_t*)(xs4 + (((size_t)n * PH + (h0 + row + 1)) * PW) * PIX4);
        orow32[(pwl + 1) * 32 + k4] = r;
    }
    // border pixels pw=0 and pw=57 of both rows
    if (t < 128) {
        int row = t >> 6;
        int rem = t & 63;
        int pix = (rem < 32) ? 0 : (PW - 1);
        uint32_t* orow32 = (uint32_t*)(xs4 + (((size_t)n * PH + (h0 + row + 1)) * PW) * PIX4);
        orow32[pix * 32 + (rem & 31)] = 0u;
    }
    // border rows ph=0 and ph=57
    if (h0 == 0) {
        uint32_t* z = (uint32_t*)(xs4 + ((size_t)n * PH * PW) * PIX4);
        for (int i = t; i < PW * 32; i += 512) z[i] = 0u;
    }
    if (h0 == HH - 2) {
        uint32_t* z = (uint32_t*)(xs4 + (((size_t)n * PH + (PH - 1)) * PW) * PIX4);
        for (int i = t; i < PW * 32; i += 512) z[i] = 0u;
    }
}

// wsB4: [o][t][c/2] fp4-pair bytes (row = 1152 B)
__global__ __launch_bounds__(128) void pack_wsB4_kernel(const float* __restrict__ wgt,
                                                        uint8_t* __restrict__ wsB4) {
    int j = threadIdx.x;           // channel pair
    int o = blockIdx.x;
    const float* s0 = wgt + ((size_t)o * CC + 2 * j) * 9;
    const float* s1 = wgt + ((size_t)o * CC + 2 * j + 1) * 9;
#pragma unroll
    for (int t = 0; t < 9; ++t)
        wsB4[(size_t)o * BROW4 + t * 128 + j] = (uint8_t)(nib4(s0[t]) | (nib4(s1[t]) << 4));
}

// ============================ MFMA GEMM (MX-FP4, verified R14-R16) ==================
// Block = 8 waves (2M x 4N), 512 threads. Tile 128 px x 256 ch, K-tile = 128 elems
// (64 B/row). 18 K-tiles. LDS: A[2][128*64]=16KB + B[2][256*64]=32KB dbuf;
// STAGE = 3 gload16/thread. Counted vmcnt(3). Swizzle bit-exact since R9.

#define STAGE(BUF, KT) do {                                                  \
    const int _t = (KT) >> 1, _q = (KT) & 1;                                 \
    const uint32_t _at = (uint32_t)(((_t / 3) * PW + (_t % 3)) * PIX4 + _q * 64); \
    const uint32_t _bt = (uint32_t)(_t * 128 + _q * 64);                     \
    gload16(xs4 + (apb0 + _at), &Asm[BUF][wid * 1024]);                      \
    gload16(wsB4 + (bpb0 + _bt), &Bsm[BUF][wid * 1024]);                     \
    gload16(wsB4 + (bpb1 + _bt), &Bsm[BUF][8192 + wid * 1024]);              \
} while (0)

#define COMPUTE(BUF) do {                                                    \
    const uint8_t* _Ab = &Asm[BUF][0];                                       \
    const uint8_t* _Bb = &Bsm[BUF][0];                                       \
    i32x4 af[4], bf[4];                                                      \
    _Pragma("unroll")                                                        \
    for (int _s = 0; _s < 4; ++_s) af[_s] = *(const i32x4*)(_Ab + swzA[_s]); \
    _Pragma("unroll")                                                        \
    for (int _u = 0; _u < 4; ++_u) bf[_u] = *(const i32x4*)(_Bb + swzB[_u]); \
    WAITLGKM0();                                                             \
    __builtin_amdgcn_sched_barrier(0);                                      \
    _Pragma("unroll")                                                        \
    for (int _s = 0; _s < 4; ++_s) {                                         \
        i32x8 _a8 = (i32x8){af[_s].x, af[_s].y, af[_s].z, af[_s].w, 0, 0, 0, 0}; \
        _Pragma("unroll")                                                    \
        for (int _u = 0; _u < 4; ++_u) {                                     \
            i32x8 _b8 = (i32x8){bf[_u].x, bf[_u].y, bf[_u].z, bf[_u].w, 0, 0, 0, 0}; \
            acc[_s][_u] = __builtin_amdgcn_mfma_scale_f32_16x16x128_f8f6f4(  \
                _a8, _b8, acc[_s][_u], 4, 4, 0, 0x7F7F7F7F, 0, 0x7F7F7F7F);  \
        }                                                                    \
    }                                                                        \
} while (0)

__global__ __launch_bounds__(512, 3) void bconv_mfma_kernel(const uint8_t* __restrict__ xs4,
                                                            const uint8_t* __restrict__ wsB4,
                                                            const float* __restrict__ bias,
                                                            float* __restrict__ out) {
    __shared__ __align__(16) uint8_t Asm[2][128 * 64];   // 8 KB each
    __shared__ __align__(16) uint8_t Bsm[2][256 * 64];   // 16 KB each

    const int m   = blockIdx.x;            // 0..783 M-tile (BN = whole N)
    const int tid = threadIdx.x;           // 0..511
    const int l   = tid & 63;
    const int wid = tid >> 6;              // 0..7
    const int lg  = l >> 4;                // k-group 0..3 (32 fp4 elems each)
    const int lr  = l & 15;                // row (A) / col (B,C)
    const int wm  = wid & 1, wn = wid >> 1;   // 2 x 4 wave grid

    const int M0 = m * 128;

    // ---- staging addresses: thread handles row tid>>2, chunk tid&3 -----------------
    const int srow0 = tid >> 2;                       // 0..127
    const int g16   = (((tid & 3) ^ ((tid >> 3) & 3)) << 4);
    uint32_t apb0, bpb0, bpb1;
    {
        int p0 = M0 + srow0;
        int n0 = p0 / SS, sp0 = p0 - n0 * SS, h0 = sp0 / WW, w0 = sp0 - h0 * WW;
        apb0 = (uint32_t)(((n0 * PH + h0) * PW + w0) * PIX4 + g16);
        bpb0 = (uint32_t)((srow0) * BROW4 + g16);
        bpb1 = (uint32_t)((128 + srow0) * BROW4 + g16);
    }

    // ---- ds_read offsets (swizzled) ------------------------------------------------
    const int swz16 = ((lg ^ ((lr >> 1) & 3)) << 4);
    int swzA[4], swzB[4];
#pragma unroll
    for (int s = 0; s < 4; ++s) swzA[s] = (wm * 64 + s * 16 + lr) * 64 + swz16;
#pragma unroll
    for (int u = 0; u < 4; ++u) swzB[u] = (wn * 64 + u * 16 + lr) * 64 + swz16;

    f32x4 acc[4][4];
#pragma unroll
    for (int s = 0; s < 4; ++s)
#pragma unroll
        for (int u = 0; u < 4; ++u)
            acc[s][u] = (f32x4){0.f, 0.f, 0.f, 0.f};

    // ---- K-loop: 18 tiles of K=128, dbuf, counted vmcnt ----------------------------
    STAGE(0, 0);
    int cur = 0;
#pragma unroll 1
    for (int kt = 0; kt < 17; ++kt) {
        STAGE(cur ^ 1, kt + 1);            // 6 outstanding
        WAITVM(3);                         // tile kt landed; kt+1 stays in flight
        __builtin_amdgcn_s_barrier();
        COMPUTE(cur);
        WAITLGKM0();
        __builtin_amdgcn_sched_barrier(0);
        __builtin_amdgcn_s_barrier();      // gates next STAGE's overwrite of cur
        cur ^= 1;
    }
    WAITVM(0);
    __builtin_amdgcn_s_barrier();
    COMPUTE(cur);

    // ---- epilogue: C/D col=lr, row=lg*4+reg (verified, shape-determined) -----------
    float bo[4];
#pragma unroll
    for (int u = 0; u < 4; ++u) bo[u] = bias[wn * 64 + u * 16 + lr];

#pragma unroll
    for (int s = 0; s < 4; ++s) {
        int pst = M0 + wm * 64 + s * 16 + lg * 4;
        int n   = pst / SS;
        int sp  = pst - n * SS;
#pragma unroll
        for (int u = 0; u < 4; ++u) {
            f32x4 a = acc[s][u];
            int o = wn * 64 + u * 16 + lr;
            float v0 = a.x + bo[u];
            float v1 = a.y + bo[u];
            float v2 = a.z + bo[u];
            float v3 = a.w + bo[u];
            float4 r4;
            r4.x = (v0 > 0.f) ? 1.f : ((v0 < 0.f) ? -1.f : 0.f);
            r4.y = (v1 > 0.f) ? 1.f : ((v1 < 0.f) ? -1.f : 0.f);
            r4.z = (v2 > 0.f) ? 1.f : ((v2 < 0.f) ? -1.f : 0.f);
            r4.w = (v3 > 0.f) ? 1.f : ((v3 < 0.f) ? -1.f : 0.f);
            *(float4*)(out + ((size_t)(n * OO + o)) * SS + sp) = r4;
        }
    }
}

// ============================ fallback popcount path (R4, 163 us) ===================

#define SPAD (PH*PW)
#define CWN  4

__global__ __launch_bounds__(256) void pack_x_kernel(const float* __restrict__ x,
                                                     uint64_t* __restrict__ px) {
    int tid = threadIdx.x;
    int sp  = blockIdx.x * 256 + tid;
    int cw  = blockIdx.y;
    int n   = blockIdx.z;
    if (sp >= SPAD) return;
    int ph = sp / PW, pw_ = sp % PW;
    uint64_t* dst = px + (((size_t)n * CWN + cw) * SPAD + sp);
    if (ph == 0 || ph == PH - 1 || pw_ == 0 || pw_ == PW - 1) { *dst = 0ull; return; }
    int h = ph - 1, w = pw_ - 1;
    const float* src = x + ((size_t)(n * CC + cw * 64)) * SS + (h * WW + w);
    uint32_t lo = 0u, hi = 0u;
#pragma unroll
    for (int j = 0; j < 32; ++j) { float v = src[(size_t)j * SS];        lo |= (v > 0.0f ? 1u : 0u) << j; }
#pragma unroll
    for (int j = 0; j < 32; ++j) { float v = src[(size_t)(j + 32) * SS]; hi |= (v > 0.0f ? 1u : 0u) << j; }
    *dst = ((uint64_t)hi << 32) | (uint64_t)lo;
}

__global__ __launch_bounds__(256) void pack_w_kernel(const float* __restrict__ wgt,
                                                     uint64_t* __restrict__ pwb) {
    int lane = threadIdx.x & 63;
    int wave = threadIdx.x >> 6;
    int wi   = blockIdx.x * 4 + wave;
    if (wi >= OO * 9 * CWN) return;
    int o = wi / 36, rem = wi % 36, t = rem >> 2, cw = rem & 3;
    int c = cw * 64 + lane;
    float v = wgt[(size_t)(o * CC + c) * 9 + t];
    uint64_t m = __ballot(v > 0.0f);
    if (lane == 0) pwb[wi] = m;
}

__global__ __launch_bounds__(256) void build_k_kernel(const uint64_t* __restrict__ pwb,
                                                      int* __restrict__ ktab) {
    int o = threadIdx.x;
    int pops[9];
#pragma unroll
    for (int t = 0; t < 9; ++t) {
        int p = 0;
#pragma unroll
        for (int cw = 0; cw < 4; ++cw) p += __popcll(pwb[o * 36 + t * 4 + cw]);
        pops[t] = p;
    }
#pragma unroll
    for (int cls = 0; cls < 9; ++cls) {
        int vf = cls / 3, hf = cls % 3;
        int K = 9 * CC;
#pragma unroll
        for (int t = 0; t < 9; ++t) {
            int r = t / 3, k = t % 3;
            bool inv = (vf == 1 && r == 0) || (vf == 2 && r == 2) ||
                       (hf == 1 && k == 0) || (hf == 2 && k == 2);
            if (inv) K -= (CC - 2 * pops[t]);
        }
        ktab[cls * OO + o] = K;
    }
}

__global__ __launch_bounds__(256, 4) void bconv_kernel(const uint64_t* __restrict__ px,
                                                       const uint64_t* __restrict__ pwb,
                                                       const int* __restrict__ ktab,
                                                       const float* __restrict__ bias,
                                                       float* __restrict__ out) {
    int g = blockIdx.x * 256 + threadIdx.x;
    int n = g / SS;
    int sid = g - n * SS;
    int obase = blockIdx.y * 32;
    int h = sid / WW, w = sid - h * WW;
    int vf = (h == 0) ? 1 : ((h == HH - 1) ? 2 : 0);
    int hf = (w == 0) ? 1 : ((w == WW - 1) ? 2 : 0);
    const int* krow = ktab + (vf * 3 + hf) * OO + obase;
    const uint64_t* pb = px + (size_t)n * CWN * SPAD + h * PW + w;
    const uint32_t* wb = (const uint32_t*)pwb + (size_t)obase * 72;
    uint32_t acc[32];
#pragma unroll
    for (int i = 0; i < 32; ++i) acc[i] = 0u;
#pragma unroll 1
    for (int r = 0; r < 3; ++r) {
#pragma unroll 1
        for (int k = 0; k < 3; ++k) {
            int off = r * PW + k;
            uint64_t q0 = pb[off];
            uint64_t q1 = pb[SPAD + off];
            uint64_t q2 = pb[2 * SPAD + off];
            uint64_t q3 = pb[3 * SPAD + off];
            uint32_t pa0 = (uint32_t)q0, pa1 = (uint32_t)(q0 >> 32);
            uint32_t pa2 = (uint32_t)q1, pa3 = (uint32_t)(q1 >> 32);
            uint32_t pa4 = (uint32_t)q2, pa5 = (uint32_t)(q2 >> 32);
            uint32_t pa6 = (uint32_t)q3, pa7 = (uint32_t)(q3 >> 32);
            int t8 = (r * 3 + k) * 8;
#pragma unroll
            for (int oi = 0; oi < 32; ++oi) {
                const uint32_t* wv = wb + oi * 72 + t8;
                uint32_t a = acc[oi];
                a = __popc(pa0 ^ wv[0]) + a;
                a = __popc(pa1 ^ wv[1]) + a;
                a = __popc(pa2 ^ wv[2]) + a;
                a = __popc(pa3 ^ wv[3]) + a;
                a = __popc(pa4 ^ wv[4]) + a;
                a = __popc(pa5 ^ wv[5]) + a;
                a = __popc(pa6 ^ wv[6]) + a;
                a = __popc(pa7 ^ wv[7]) + a;
                acc[oi] = a;
            }
        }
    }
    float* orow = out + ((size_t)(n * OO + obase)) * SS + sid;
#pragma unroll
    for (int oi = 0; oi < 32; ++oi) {
        int s = krow[oi] - 2 * (int)acc[oi];
        float v = (float)s + bias[obase + oi];
        float res = (v > 0.0f) ? 1.0f : ((v < 0.0f) ? -1.0f : 0.0f);
        orow[(size_t)oi * SS] = res;
    }
}

// ============================ launch ================================================

extern "C" void kernel_launch(void* const* d_in, const int* in_sizes, int n_in,
                              void* d_out, int out_size, void* d_ws, size_t ws_size,
                              hipStream_t stream) {
    const float* x    = (const float*)d_in[0];
    const float* wgt  = (const float*)d_in[1];
    const float* bias = (const float*)d_in[2];
    float* out = (float*)d_out;

    const size_t wsB4_bytes = (size_t)OO * BROW4;               // 294,912
    const size_t xs4_bytes  = (size_t)NB * PH * PW * PIX4;      // 13,778,944
    if (ws_size >= wsB4_bytes + xs4_bytes) {
        uint8_t* wsB4 = (uint8_t*)d_ws;
        uint8_t* xs4  = (uint8_t*)d_ws + wsB4_bytes;
        pack_xs4_kernel<<<dim3(HH / 2, NB), 512, 0, stream>>>(x, xs4);
        pack_wsB4_kernel<<<dim3(OO), 128, 0, stream>>>(wgt, wsB4);
        const int n_blocks = NB * SS / 128;                     // 784 (BN = whole N)
        bconv_mfma_kernel<<<dim3(n_blocks), 512, 0, stream>>>(xs4, wsB4, bias, out);
    } else {
        // fallback: proven popcount path (R4)
        size_t px_bytes = (size_t)NB * CWN * SPAD * 8;
        size_t pw_off   = px_bytes;
        size_t pw_bytes = (size_t)OO * 9 * CWN * 8;
        size_t k_off    = pw_off + pw_bytes;
        uint64_t* px  = (uint64_t*)d_ws;
        uint64_t* pwb = (uint64_t*)((char*)d_ws + pw_off);
        int*      kt  = (int*)((char*)d_ws + k_off);
        dim3 gpx((SPAD + 255) / 256, CWN, NB);
        pack_x_kernel<<<gpx, 256, 0, stream>>>(x, px);
        int nwords = OO * 9 * CWN;
        pack_w_kernel<<<dim3((nwords + 3) / 4), 256, 0, stream>>>(wgt, pwb);
        build_k_kernel<<<dim3(1), 256, 0, stream>>>(pwb, kt);
        dim3 gcv(NB * SS / 256, OO / 32, 1);
        bconv_kernel<<<gcv, 256, 0, stream>>>(px, pwb, kt, bias, out);
    }
}